// Round 4
// baseline (762.142 us; speedup 1.0000x reference)
//
#include <hip/hip_runtime.h>
#include <cstdint>
#include <cstddef>

// Problem constants (from reference)
#define BN_ 2
#define TQ_ 1024
#define TK_ 2048
#define DQ_ 1024
#define DC_ 768
#define NH_ 16
#define DH_ 64
#define TOPK_ 64

typedef unsigned short u16;
typedef __attribute__((ext_vector_type(8))) short short8;   // 8 bf16 MFMA frag
typedef __attribute__((ext_vector_type(8))) u16   ushort8;  // 16B vector load
typedef __attribute__((ext_vector_type(4))) float floatx4;  // MFMA acc / float4

__device__ __forceinline__ float bf2f(u16 u) { return __uint_as_float(((unsigned)u) << 16); }
__device__ __forceinline__ u16 f2bf(float f) {  // round-to-nearest-even
    unsigned u = __float_as_uint(f);
    u += 0x7FFFu + ((u >> 16) & 1u);
    return (u16)(u >> 16);
}
__device__ __forceinline__ float definite(float v, float repl) {
    return ((__float_as_uint(v) & 0x7F800000u) == 0x7F800000u) ? repl : v;
}
__device__ __forceinline__ unsigned mono(float f) {
    unsigned u = __float_as_uint(f);
    return (u & 0x80000000u) ? ~u : (u | 0x80000000u);
}
__device__ __forceinline__ int wave_sum(int x) {
#pragma unroll
    for (int o = 32; o; o >>= 1) x += __shfl_xor(x, o);
    return x;
}
__device__ __forceinline__ int wave_min_i(int x) {
#pragma unroll
    for (int o = 32; o; o >>= 1) { int y = __shfl_xor(x, o); x = (y < x) ? y : x; }
    return x;
}

// ---------------------------------------------------------------------------
// Float-layout probe: returns 1 if buffer holds fp32, 0 if bf16.
// Looks at 32 even-indexed u16. True-bf16 N(0,sigma) data: nonzero, exponent
// field in a sane band -> ~32 hits. fp32 data: even u16 are low mantissa bits
// (uniform -> ~6 hits) or exactly 0 (fp32 storing bf16-rounded values).
__device__ __forceinline__ int probe_is_f32(const u16* __restrict__ p) {
    int sane = 0;
#pragma unroll
    for (int j = 0; j < 32; ++j) {
        const unsigned v = p[2 * j];
        const unsigned e = (v >> 7) & 0xFFu;
        sane += (v != 0u && e >= 0x58u && e <= 0x86u) ? 1 : 0;
    }
    return sane < 24 ? 1 : 0;
}

// diagnostic: fill output with a recognizable constant
__global__ void marker_kernel(u16* __restrict__ out, int n, float val) {
    const int i = blockIdx.x * 256 + threadIdx.x;
    if (i < n) out[i] = f2bf(val);
}

// ---------------------------------------------------------------------------
// GEMM: C[M][N] = A[M][K] * W[K][N] + bias, then * scale. A/W dtype detected
// per-block (fp32 -> hi/lo bf16 split staging + 3-term MFMA, ~fp32 accurate).
// OMODE 1: bf16 out. OMODE 2: bf16 hi/lo pair out. OMODE 3: out dtype = W dtype.
// 64x64 tile, BK=64, 4 waves 2x2, each wave 32x32 via 2x2 mfma_16x16x32.
template <int OMODE>
__global__ void __launch_bounds__(256) gemm_dyn(
    const void* __restrict__ Ap, const void* __restrict__ Wp,
    const void* __restrict__ biasp, float scale,
    void* __restrict__ out0, void* __restrict__ out1,
    int M, int N, int K, int aForceBf16) {
    alignas(16) __shared__ u16 Ah[64][72];  // [m][k] hi
    alignas(16) __shared__ u16 Al[64][72];  // [m][k] lo (fp32 mode only)
    alignas(16) __shared__ u16 Wh[64][72];  // [k][n] hi
    alignas(16) __shared__ u16 Wl[64][72];  // [k][n] lo (fp32 mode only)

    const int amode = aForceBf16 ? 0 : probe_is_f32((const u16*)Ap);
    const int wmode = probe_is_f32((const u16*)Wp);

    const int tid = threadIdx.x;
    const int lane = tid & 63, wave = tid >> 6;
    const int wm = wave >> 1, wn = wave & 1;
    const int quad = lane >> 4, l16 = lane & 15;
    const int bm = blockIdx.y * 64, bn = blockIdx.x * 64;

    floatx4 acc[2][2] = {};
    const int r0 = tid >> 3;          // 0..31
    const int c0 = (tid & 7) << 3;    // 0..56 step 8

    for (int k0 = 0; k0 < K; k0 += 64) {
        __syncthreads();
        // ---- stage A rows r0, r0+32 (8 elements each)
#pragma unroll
        for (int h = 0; h < 2; ++h) {
            const int r = r0 + h * 32;
            const size_t eoff = (size_t)(bm + r) * K + k0 + c0;
            if (!amode) {
                *(ushort8*)&Ah[r][c0] = *(const ushort8*)((const u16*)Ap + eoff);
            } else {
                const float* f = (const float*)Ap + eoff;
                floatx4 a = *(const floatx4*)f;
                floatx4 b = *(const floatx4*)(f + 4);
#pragma unroll
                for (int j = 0; j < 4; ++j) {
                    u16 hh = f2bf(a[j]);
                    Ah[r][c0 + j] = hh;
                    Al[r][c0 + j] = f2bf(a[j] - bf2f(hh));
                    hh = f2bf(b[j]);
                    Ah[r][c0 + 4 + j] = hh;
                    Al[r][c0 + 4 + j] = f2bf(b[j] - bf2f(hh));
                }
            }
        }
        // ---- stage W rows (k-dim) r0, r0+32
#pragma unroll
        for (int h = 0; h < 2; ++h) {
            const int r = r0 + h * 32;
            const size_t eoff = (size_t)(k0 + r) * N + bn + c0;
            if (!wmode) {
                *(ushort8*)&Wh[r][c0] = *(const ushort8*)((const u16*)Wp + eoff);
            } else {
                const float* f = (const float*)Wp + eoff;
                floatx4 a = *(const floatx4*)f;
                floatx4 b = *(const floatx4*)(f + 4);
#pragma unroll
                for (int j = 0; j < 4; ++j) {
                    u16 hh = f2bf(a[j]);
                    Wh[r][c0 + j] = hh;
                    Wl[r][c0 + j] = f2bf(a[j] - bf2f(hh));
                    hh = f2bf(b[j]);
                    Wh[r][c0 + 4 + j] = hh;
                    Wl[r][c0 + 4 + j] = f2bf(b[j] - bf2f(hh));
                }
            }
        }
        __syncthreads();
#pragma unroll
        for (int s = 0; s < 2; ++s) {
            short8 ah[2], al[2];
#pragma unroll
            for (int mt = 0; mt < 2; ++mt) {
                ah[mt] = *(const short8*)&Ah[wm * 32 + mt * 16 + l16][s * 32 + quad * 8];
                if (amode) al[mt] = *(const short8*)&Al[wm * 32 + mt * 16 + l16][s * 32 + quad * 8];
            }
            short8 wh[2], wl[2];
#pragma unroll
            for (int nt = 0; nt < 2; ++nt) {
                const int ncol = wn * 32 + nt * 16 + l16;
#pragma unroll
                for (int j = 0; j < 8; ++j) {
                    wh[nt][j] = (short)Wh[s * 32 + quad * 8 + j][ncol];
                    if (wmode) wl[nt][j] = (short)Wl[s * 32 + quad * 8 + j][ncol];
                }
            }
#pragma unroll
            for (int mt = 0; mt < 2; ++mt)
#pragma unroll
                for (int nt = 0; nt < 2; ++nt) {
                    acc[mt][nt] = __builtin_amdgcn_mfma_f32_16x16x32_bf16(ah[mt], wh[nt], acc[mt][nt], 0, 0, 0);
                    if (amode)
                        acc[mt][nt] = __builtin_amdgcn_mfma_f32_16x16x32_bf16(al[mt], wh[nt], acc[mt][nt], 0, 0, 0);
                    if (wmode)
                        acc[mt][nt] = __builtin_amdgcn_mfma_f32_16x16x32_bf16(ah[mt], wl[nt], acc[mt][nt], 0, 0, 0);
                }
        }
    }

#pragma unroll
    for (int mt = 0; mt < 2; ++mt) {
#pragma unroll
        for (int nt = 0; nt < 2; ++nt) {
            const int col = bn + wn * 32 + nt * 16 + l16;
            const float bcol = wmode ? ((const float*)biasp)[col]
                                     : bf2f(((const u16*)biasp)[col]);
#pragma unroll
            for (int r = 0; r < 4; ++r) {
                const int row = bm + wm * 32 + mt * 16 + quad * 4 + r;
                const float val = definite((acc[mt][nt][r] + bcol) * scale, 0.0f);
                const size_t idx = (size_t)row * N + col;
                if constexpr (OMODE == 1) {
                    ((u16*)out0)[idx] = f2bf(val);
                } else if constexpr (OMODE == 2) {
                    const u16 hi = f2bf(val);
                    ((u16*)out0)[idx] = hi;
                    ((u16*)out1)[idx] = f2bf(val - bf2f(hi));
                } else {  // OMODE 3: out dtype follows W dtype
                    if (wmode) ((float*)out0)[idx] = val;
                    else       ((u16*)out0)[idx] = f2bf(val);
                }
            }
        }
    }
}

// ---------------------------------------------------------------------------
// Fused attention: per WG = one (b, h, 16-query tile).
// Split-bf16 MFMA logits (fp32-accurate top-64 selection vs fp32 reference).
// 4 quarters of 512 keys; exact streaming top-64 via bitwise binary search on
// monotone-uint + 64-entry carry; tie-fill ascending key (lax.top_k order).
// Mask dtype probed per-block (int32/byte/bf16/fp32). Output written IN-PLACE
// over Qhi (each WG writes exactly the 16x64 block only it reads) — no
// __restrict__ on those two params (they alias).
__global__ void __launch_bounds__(256) attn_topk(
    const u16* Qhi, const u16* __restrict__ Qlo,
    const u16* __restrict__ Khi, const u16* __restrict__ Klo,
    const u16* __restrict__ Vb16, const void* __restrict__ maskp,
    u16* attn_out) {
    alignas(16) __shared__ float lg[16][516];     // 16 q-rows x 512 keys (+4 pad)
    alignas(16) __shared__ float cval[16][64];    // carry: values
    alignas(16) __shared__ int   ckey[16][64];    // carry: key indices
    __shared__ int mbits;

    const int tid = threadIdx.x;
    const int lane = tid & 63, wave = tid >> 6;
    const int quad = lane >> 4, l16 = lane & 15;
    const int b = blockIdx.z, h = blockIdx.y, q0 = blockIdx.x * 16;

    // ---- mask dtype probe over first 1024 u16 (2 KB; min mask buf is 4 KB)
    if (tid == 0) mbits = 0;
    __syncthreads();
    {
        int bits = 0;
        for (int i = tid; i < 1024; i += 256) {
            const unsigned v = ((const u16*)maskp)[i];
            if (v == 0x0100u || v == 0x0101u) bits |= 1;   // byte-pair with high-byte one
            if ((i & 1) && v == 0x0001u) bits |= 1;        // odd u16 == 1 -> byte
            if (!(i & 1) && v == 0x3F80u) bits |= 2;       // bf16 1.0 at even
            if ((i & 1) && v == 0x3F80u) bits |= 4;        // fp32 1.0f high half
        }
        if (bits) atomicOr(&mbits, bits);
    }

    // Q fragments (A-operand: m=lane&15, k=quad*8+j), two k-steps of 32
    short8 qh[2], ql[2];
    {
        const size_t base = (size_t)(b * TQ_ + q0 + l16) * DQ_ + h * DH_ + quad * 8;
        qh[0] = *(const short8*)(Qhi + base);
        qh[1] = *(const short8*)(Qhi + base + 32);
        ql[0] = *(const short8*)(Qlo + base);
        ql[1] = *(const short8*)(Qlo + base + 32);
    }

    // init carry to -inf with distinct keys
    for (int i = tid; i < 16 * 64; i += 256) {
        cval[i >> 6][i & 63] = __uint_as_float(0xFF800000u);
        ckey[i >> 6][i & 63] = i & 63;
    }
    __syncthreads();
    const int fb = mbits;
    const int mmode = (fb & 2) ? 2 : (fb & 4) ? 3 : (fb & 1) ? 1 : 0;

    for (int qtr = 0; qtr < 4; ++qtr) {
        __syncthreads();
        // ---- logits for keys [qtr*512 .. +512), each wave handles 128 keys
        for (int t = 0; t < 8; ++t) {
            const int key = qtr * 512 + wave * 128 + t * 16 + l16;
            const size_t kb = (size_t)(b * TK_ + key) * DQ_ + h * DH_ + quad * 8;
            const short8 kh0 = *(const short8*)(Khi + kb);
            const short8 kh1 = *(const short8*)(Khi + kb + 32);
            const short8 kl0 = *(const short8*)(Klo + kb);
            const short8 kl1 = *(const short8*)(Klo + kb + 32);
            floatx4 acc = {};
            acc = __builtin_amdgcn_mfma_f32_16x16x32_bf16(qh[0], kh0, acc, 0, 0, 0);
            acc = __builtin_amdgcn_mfma_f32_16x16x32_bf16(ql[0], kh0, acc, 0, 0, 0);
            acc = __builtin_amdgcn_mfma_f32_16x16x32_bf16(qh[0], kl0, acc, 0, 0, 0);
            acc = __builtin_amdgcn_mfma_f32_16x16x32_bf16(qh[1], kh1, acc, 0, 0, 0);
            acc = __builtin_amdgcn_mfma_f32_16x16x32_bf16(ql[1], kh1, acc, 0, 0, 0);
            acc = __builtin_amdgcn_mfma_f32_16x16x32_bf16(qh[1], kl1, acc, 0, 0, 0);
            const int midx = b * TK_ + key;
            bool masked;
            if (mmode == 2)      masked = ((const u16*)maskp)[midx] != 0;
            else if (mmode == 3) masked = ((const float*)maskp)[midx] != 0.0f;
            else if (mmode == 1) masked = ((const unsigned char*)maskp)[midx] != 0;
            else                 masked = ((const int*)maskp)[midx] != 0;
            const int kk = wave * 128 + t * 16 + l16;
#pragma unroll
            for (int r = 0; r < 4; ++r)
                lg[quad * 4 + r][kk] = masked ? -3.0e38f : definite(acc[r], -3.0e38f);
        }
        __syncthreads();
        // ---- streaming top-64 merge, each wave owns 4 rows
        for (int rr = 0; rr < 4; ++rr) {
            const int row = wave * 4 + rr;
            float fv[9]; int kidx[9]; unsigned u[9];
#pragma unroll
            for (int j = 0; j < 8; ++j) {
                fv[j] = lg[row][lane + 64 * j];
                kidx[j] = qtr * 512 + lane + 64 * j;
            }
            fv[8] = cval[row][lane];
            kidx[8] = ckey[row][lane];
#pragma unroll
            for (int j = 0; j < 9; ++j) u[j] = mono(fv[j]);

            // X := max T s.t. count(u >= T) >= 64  (== 64th largest value)
            unsigned X = 0u;
            for (int bit = 31; bit >= 0; --bit) {
                const unsigned C = X | (1u << bit);
                int c = 0;
#pragma unroll
                for (int j = 0; j < 9; ++j) c += (u[j] >= C) ? 1 : 0;
                c = wave_sum(c);
                if (c >= 64) { X = C; if (c == 64) break; }
            }
            // compact strictly-greater elements
            int cgt = 0;
            float xval = 0.f;
#pragma unroll
            for (int j = 0; j < 9; ++j) {
                cgt += (u[j] > X) ? 1 : 0;
                if (u[j] == X) xval = fv[j];
            }
            int pre = cgt;
            for (int off = 1; off < 64; off <<= 1) {
                int tv = __shfl_up(pre, off);
                if (lane >= off) pre += tv;
            }
            const int total_gt = __shfl(pre, 63);
            int wpos = pre - cgt;
#pragma unroll
            for (int j = 0; j < 9; ++j)
                if (u[j] > X) { cval[row][wpos] = fv[j]; ckey[row][wpos] = kidx[j]; ++wpos; }
            // fill remaining slots with ==X ties, ascending key index
            int remaining = 64 - total_gt;
            int pos = total_gt;
            int lastkey = -1;
            while (remaining > 0) {
                int mykey = 0x7FFFFFFF;
#pragma unroll
                for (int j = 0; j < 9; ++j)
                    if (u[j] == X && kidx[j] > lastkey && kidx[j] < mykey) mykey = kidx[j];
                const int mn = wave_min_i(mykey);
                if (mn == 0x7FFFFFFF) break;
                if (mykey == mn) { cval[row][pos] = xval; ckey[row][pos] = mn; }
                lastkey = mn;
                ++pos; --remaining;
            }
        }
    }
    __syncthreads();

    // ---- softmax over 64 kept entries + weighted bf16-V gather
    for (int rr = 0; rr < 4; ++rr) {
        const int row = wave * 4 + rr;
        const float v = cval[row][lane];
        const int k = ckey[row][lane];
        float m = v;
#pragma unroll
        for (int off = 32; off; off >>= 1) m = fmaxf(m, __shfl_xor(m, off));
        const float p = __expf(v - m);
        float s = p;
#pragma unroll
        for (int off = 32; off; off >>= 1) s += __shfl_xor(s, off);
        const float w = p / s;
        float av = 0.f;
        const u16* Vp = Vb16 + (size_t)(b * TK_) * DQ_ + h * DH_ + lane;
#pragma unroll 8
        for (int e = 0; e < 64; ++e) {
            const float we = __shfl(w, e);
            const int ke = __shfl(k, e);
            av += we * bf2f(Vp[(size_t)ke * DQ_]);
        }
        av = definite(av, 0.0f);
        attn_out[(size_t)(b * TQ_ + q0 + row) * DQ_ + h * DH_ + lane] = f2bf(av);
    }
}

// ---------------------------------------------------------------------------
extern "C" void kernel_launch(void* const* d_in, const int* in_sizes, int n_in,
                              void* d_out, int out_size, void* d_ws, size_t ws_size,
                              hipStream_t stream) {
    // ---- sanity: element counts must match the reference's setup_inputs order
    static const int exp_sizes[11] = {2097152, 3145728, 4096, 1048576, 1024,
                                      786432, 1024, 786432, 1024, 1048576, 1024};
    if (n_in != 11) {
        marker_kernel<<<(out_size + 255) / 256, 256, 0, stream>>>((u16*)d_out, out_size,
                                                                  (float)(150 + n_in));
        return;
    }
    for (int i = 0; i < 11; ++i)
        if (in_sizes[i] != exp_sizes[i]) {
            marker_kernel<<<(out_size + 255) / 256, 256, 0, stream>>>((u16*)d_out, out_size,
                                                                      (float)(200 + i));
            return;
        }

    const void* x   = d_in[0];
    const void* ctx = d_in[1];
    const void* msk = d_in[2];
    const void* Wq = d_in[3];
    const void* bq = d_in[4];
    const void* Wk = d_in[5];
    const void* bk = d_in[6];
    const void* Wv = d_in[7];
    const void* bv = d_in[8];
    const void* Wo = d_in[9];
    const void* bo = d_in[10];

    // ---- workspace: exactly 32 MB (verified available in round 3)
    const size_t SZ_Q = (size_t)BN_ * TQ_ * DQ_ * 2;   // 4 MB
    const size_t SZ_K = (size_t)BN_ * TK_ * DQ_ * 2;   // 8 MB
    const size_t NEED = 2 * SZ_Q + 2 * SZ_K + SZ_K;    // 32 MB
    if (ws_size < NEED) {
        marker_kernel<<<(out_size + 255) / 256, 256, 0, stream>>>(
            (u16*)d_out, out_size, (float)(ws_size >> 20));
        return;
    }

    char* ws = (char*)d_ws;
    u16* Qhi = (u16*)(ws);
    u16* Qlo = (u16*)(ws + SZ_Q);
    u16* Khi = (u16*)(ws + 2 * SZ_Q);
    u16* Klo = (u16*)(ws + 2 * SZ_Q + SZ_K);
    u16* Vb  = (u16*)(ws + 2 * SZ_Q + 2 * SZ_K);
    u16* attn = Qhi;  // in-place: each attn WG overwrites exactly the block it read

    const int MQ = BN_ * TQ_;  // 2048
    const int MK = BN_ * TK_;  // 4096
    // Q projection scaled by DH^-0.5 (folded into hi/lo split)
    gemm_dyn<2><<<dim3(DQ_ / 64, MQ / 64), 256, 0, stream>>>(x,   Wq, bq, 0.125f, Qhi, Qlo, MQ, DQ_, DQ_, 0);
    gemm_dyn<2><<<dim3(DQ_ / 64, MK / 64), 256, 0, stream>>>(ctx, Wk, bk, 1.0f,   Khi, Klo, MK, DQ_, DC_, 0);
    gemm_dyn<1><<<dim3(DQ_ / 64, MK / 64), 256, 0, stream>>>(ctx, Wv, bv, 1.0f,   Vb,  nullptr, MK, DQ_, DC_, 0);

    attn_topk<<<dim3(TQ_ / 16, NH_, BN_), 256, 0, stream>>>(Qhi, Qlo, Khi, Klo, Vb, msk, attn);

    // output projection: A(=attn) is workspace bf16 (forced), out dtype follows Wo
    gemm_dyn<3><<<dim3(DQ_ / 64, MQ / 64), 256, 0, stream>>>(attn, Wo, bo, 1.0f, d_out, nullptr, MQ, DQ_, DQ_, 1);
}

// Round 5
// 510.919 us; speedup vs baseline: 1.4917x; 1.4917x over previous
//
#include <hip/hip_runtime.h>
#include <cstdint>
#include <cstddef>

// Problem constants (from reference). Inputs/outputs are fp32 (verified round 4).
#define BN_ 2
#define TQ_ 1024
#define TK_ 2048
#define DQ_ 1024
#define DC_ 768
#define NH_ 16
#define DH_ 64
#define TOPK_ 64

typedef unsigned short u16;
typedef __attribute__((ext_vector_type(8))) short short8;   // 8 bf16 MFMA frag
typedef __attribute__((ext_vector_type(8))) u16   ushort8;  // 16B vector load
typedef __attribute__((ext_vector_type(4))) float floatx4;  // MFMA acc / float4

__device__ __forceinline__ float bf2f(u16 u) { return __uint_as_float(((unsigned)u) << 16); }
__device__ __forceinline__ u16 f2bf(float f) {  // round-to-nearest-even
    unsigned u = __float_as_uint(f);
    u += 0x7FFFu + ((u >> 16) & 1u);
    return (u16)(u >> 16);
}
__device__ __forceinline__ float definite(float v, float repl) {
    return ((__float_as_uint(v) & 0x7F800000u) == 0x7F800000u) ? repl : v;
}
// monotone float<->uint mapping (ascending)
__device__ __forceinline__ unsigned mono(float f) {
    unsigned u = __float_as_uint(f);
    return (u & 0x80000000u) ? ~u : (u | 0x80000000u);
}
__device__ __forceinline__ float invmono(unsigned u) {
    return __uint_as_float((u & 0x80000000u) ? (u & 0x7FFFFFFFu) : ~u);
}
// 16-lane-group reductions (xor offsets 1,2,4,8 stay inside the group -> DPP-fast)
__device__ __forceinline__ int gsum16(int x) {
#pragma unroll
    for (int o = 1; o < 16; o <<= 1) x += __shfl_xor(x, o);
    return x;
}
__device__ __forceinline__ int gmin16(int x) {
#pragma unroll
    for (int o = 1; o < 16; o <<= 1) { int y = __shfl_xor(x, o); x = (y < x) ? y : x; }
    return x;
}
__device__ __forceinline__ float gmax16f(float x) {
#pragma unroll
    for (int o = 1; o < 16; o <<= 1) x = fmaxf(x, __shfl_xor(x, o));
    return x;
}
__device__ __forceinline__ float gsum16f(float x) {
#pragma unroll
    for (int o = 1; o < 16; o <<= 1) x += __shfl_xor(x, o);
    return x;
}

// diagnostic: fill output with a recognizable constant (fp32 out)
__global__ void marker_kernel(float* __restrict__ out, int n, float val) {
    const int i = blockIdx.x * 256 + threadIdx.x;
    if (i < n) out[i] = val;
}

// ---------------------------------------------------------------------------
// Transpose + hi/lo-split: W fp32 [K][N] -> Wh,Wl bf16 [N][K]
__global__ void __launch_bounds__(256) tsplit(const float* __restrict__ W,
                                              u16* __restrict__ Wh, u16* __restrict__ Wl,
                                              int K, int N) {
    __shared__ float t[32][33];
    const int x = threadIdx.x & 31, y = threadIdx.x >> 5;   // y in 0..7
    const int bn = blockIdx.x * 32, bk = blockIdx.y * 32;
#pragma unroll
    for (int i = 0; i < 32; i += 8) t[y + i][x] = W[(size_t)(bk + y + i) * N + bn + x];
    __syncthreads();
#pragma unroll
    for (int i = 0; i < 32; i += 8) {
        const float f = t[x][y + i];            // = W[bk+x][bn+y+i]
        const u16 hi = f2bf(f);
        const size_t o = (size_t)(bn + y + i) * K + bk + x;
        Wh[o] = hi;
        Wl[o] = f2bf(f - bf2f(hi));
    }
}

// ---------------------------------------------------------------------------
// GEMM: C[M][N] = A[M][K] * W[K][N] + bias(fp32), then * scale.
// B supplied pre-transposed & split: Bh/Bl bf16 [N][K].
// ASPLIT 0: A fp32 (split to hi/lo bf16 at stage time). ASPLIT 1: A is a bf16
// hi/lo pair (Ap=hi, Alp=lo). 3-term MFMA: ah*bh + al*bh + ah*bl (~fp32).
// OMODE 0: fp32 out. 1: bf16 out. 2: bf16 hi/lo pair out.
// 64x64 tile, BK=64, 4 waves 2x2, each wave 32x32 via 2x2 mfma_16x16x32.
template <int ASPLIT, int OMODE>
__global__ void __launch_bounds__(256) gemm2(
    const void* __restrict__ Ap, const void* __restrict__ Alp,
    const u16* __restrict__ Bh, const u16* __restrict__ Bl,
    const float* __restrict__ bias, float scale,
    void* __restrict__ out0, void* __restrict__ out1,
    int M, int N, int K) {
    alignas(16) __shared__ u16 Ah[64][72];   // [m][k] hi  (+8 pad: b128 2-way, free)
    alignas(16) __shared__ u16 Al[64][72];   // [m][k] lo
    alignas(16) __shared__ u16 Bhs[64][72];  // [n][k] hi
    alignas(16) __shared__ u16 Bls[64][72];  // [n][k] lo

    const int tid = threadIdx.x;
    const int lane = tid & 63, wave = tid >> 6;
    const int wm = wave >> 1, wn = wave & 1;
    const int quad = lane >> 4, l16 = lane & 15;
    const int bm = blockIdx.y * 64, bn = blockIdx.x * 64;

    floatx4 acc[2][2] = {};
    const int r0 = tid >> 3;          // 0..31
    const int c0 = (tid & 7) << 3;    // 0..56 step 8

    for (int k0 = 0; k0 < K; k0 += 64) {
        __syncthreads();
#pragma unroll
        for (int hh = 0; hh < 2; ++hh) {
            const int r = r0 + hh * 32;
            const size_t aoff = (size_t)(bm + r) * K + k0 + c0;
            if constexpr (ASPLIT == 0) {
                const float* f = (const float*)Ap + aoff;
                const floatx4 a = *(const floatx4*)f;
                const floatx4 b = *(const floatx4*)(f + 4);
#pragma unroll
                for (int j = 0; j < 4; ++j) {
                    u16 t = f2bf(a[j]);
                    Ah[r][c0 + j] = t; Al[r][c0 + j] = f2bf(a[j] - bf2f(t));
                    t = f2bf(b[j]);
                    Ah[r][c0 + 4 + j] = t; Al[r][c0 + 4 + j] = f2bf(b[j] - bf2f(t));
                }
            } else {
                *(ushort8*)&Ah[r][c0] = *(const ushort8*)((const u16*)Ap + aoff);
                *(ushort8*)&Al[r][c0] = *(const ushort8*)((const u16*)Alp + aoff);
            }
            const size_t boff = (size_t)(bn + r) * K + k0 + c0;
            *(ushort8*)&Bhs[r][c0] = *(const ushort8*)(Bh + boff);
            *(ushort8*)&Bls[r][c0] = *(const ushort8*)(Bl + boff);
        }
        __syncthreads();
#pragma unroll
        for (int s = 0; s < 2; ++s) {
            short8 ah[2], al[2], bh[2], bl[2];
#pragma unroll
            for (int mt = 0; mt < 2; ++mt) {
                ah[mt] = *(const short8*)&Ah[wm * 32 + mt * 16 + l16][s * 32 + quad * 8];
                al[mt] = *(const short8*)&Al[wm * 32 + mt * 16 + l16][s * 32 + quad * 8];
            }
#pragma unroll
            for (int nt = 0; nt < 2; ++nt) {
                bh[nt] = *(const short8*)&Bhs[wn * 32 + nt * 16 + l16][s * 32 + quad * 8];
                bl[nt] = *(const short8*)&Bls[wn * 32 + nt * 16 + l16][s * 32 + quad * 8];
            }
#pragma unroll
            for (int mt = 0; mt < 2; ++mt)
#pragma unroll
                for (int nt = 0; nt < 2; ++nt) {
                    acc[mt][nt] = __builtin_amdgcn_mfma_f32_16x16x32_bf16(ah[mt], bh[nt], acc[mt][nt], 0, 0, 0);
                    acc[mt][nt] = __builtin_amdgcn_mfma_f32_16x16x32_bf16(al[mt], bh[nt], acc[mt][nt], 0, 0, 0);
                    acc[mt][nt] = __builtin_amdgcn_mfma_f32_16x16x32_bf16(ah[mt], bl[nt], acc[mt][nt], 0, 0, 0);
                }
        }
    }

#pragma unroll
    for (int mt = 0; mt < 2; ++mt) {
#pragma unroll
        for (int nt = 0; nt < 2; ++nt) {
            const int col = bn + wn * 32 + nt * 16 + l16;
            const float bcol = bias[col];
#pragma unroll
            for (int r = 0; r < 4; ++r) {
                const int row = bm + wm * 32 + mt * 16 + quad * 4 + r;
                const float val = definite((acc[mt][nt][r] + bcol) * scale, 0.0f);
                const size_t idx = (size_t)row * N + col;
                if constexpr (OMODE == 0) {
                    ((float*)out0)[idx] = val;
                } else if constexpr (OMODE == 1) {
                    ((u16*)out0)[idx] = f2bf(val);
                } else {
                    const u16 hi = f2bf(val);
                    ((u16*)out0)[idx] = hi;
                    ((u16*)out1)[idx] = f2bf(val - bf2f(hi));
                }
            }
        }
    }
}

// ---------------------------------------------------------------------------
// Fused attention: per WG = one (b, h, 16-query tile).
// Split-bf16 MFMA logits (fp32-accurate top-64 selection vs fp32 reference).
// 4 quarters of 512 keys. Selection is GROUP-PARALLEL: each wave processes its
// 4 rows simultaneously (16 lanes/row, 36 values/lane incl. 4-carry); the
// 32-bit binary search's count-reduction is 4 intra-16 shfl_xor (DPP-fast)
// shared across 4 rows, with wave-uniform early exit. Tie-fill ascending key
// (lax.top_k order). Softmax group-parallel; V-gather reads (w,k) via
// uniform-address LDS broadcast. Output hi/lo written IN-PLACE over Qhi/Qlo.
__global__ void __launch_bounds__(256) attn_topk(
    const u16* Qhi, const u16* Qlo,     // aliased with outputs - no __restrict__
    const u16* __restrict__ Khi, const u16* __restrict__ Klo,
    const u16* __restrict__ Vb16, const void* __restrict__ maskp,
    u16* attnH, u16* attnL) {
    __shared__ float lg[16][520];     // 16 q-rows x 512 keys; stride 520: 2-way reads (free)
    __shared__ float cval[16][72];    // carry values (slots 0..63; stride 72: 2-way)
    __shared__ int   ckey[16][72];    // carry keys
    __shared__ int mbits;

    const int tid = threadIdx.x;
    const int lane = tid & 63, wave = tid >> 6;
    const int quad = lane >> 4, l16 = lane & 15;   // quad = row-group, l16 = sublane
    const int rowg = wave * 4 + quad;              // this lane's selection row
    const int b = blockIdx.z, h = blockIdx.y, q0 = blockIdx.x * 16;

    // ---- mask dtype probe (identical logic to the round-4 pass)
    if (tid == 0) mbits = 0;
    __syncthreads();
    {
        int bits = 0;
        for (int i = tid; i < 1024; i += 256) {
            const unsigned v = ((const u16*)maskp)[i];
            if (v == 0x0100u || v == 0x0101u) bits |= 1;
            if ((i & 1) && v == 0x0001u) bits |= 1;
            if (!(i & 1) && v == 0x3F80u) bits |= 2;
            if ((i & 1) && v == 0x3F80u) bits |= 4;
        }
        if (bits) atomicOr(&mbits, bits);
    }

    // ---- Q fragments (A-operand: m=lane&15, k=quad*8+j), two k-steps of 32
    short8 qh[2], ql[2];
    {
        const size_t base = (size_t)(b * TQ_ + q0 + l16) * DQ_ + h * DH_ + quad * 8;
        qh[0] = *(const short8*)(Qhi + base);
        qh[1] = *(const short8*)(Qhi + base + 32);
        ql[0] = *(const short8*)(Qlo + base);
        ql[1] = *(const short8*)(Qlo + base + 32);
    }

    // init carry to -inf with distinct keys
    for (int i = tid; i < 16 * 64; i += 256) {
        cval[i >> 6][i & 63] = __uint_as_float(0xFF800000u);
        ckey[i >> 6][i & 63] = i & 63;
    }
    __syncthreads();
    const int fb = mbits;
    const int mmode = (fb & 2) ? 2 : (fb & 4) ? 3 : (fb & 1) ? 1 : 0;

    for (int qtr = 0; qtr < 4; ++qtr) {
        // ---- logits for keys [qtr*512 .. +512), each wave computes 128 keys x 16 rows
        for (int t = 0; t < 8; ++t) {
            const int key = qtr * 512 + wave * 128 + t * 16 + l16;
            const size_t kb = (size_t)(b * TK_ + key) * DQ_ + h * DH_ + quad * 8;
            const short8 kh0 = *(const short8*)(Khi + kb);
            const short8 kh1 = *(const short8*)(Khi + kb + 32);
            const short8 kl0 = *(const short8*)(Klo + kb);
            const short8 kl1 = *(const short8*)(Klo + kb + 32);
            floatx4 acc = {};
            acc = __builtin_amdgcn_mfma_f32_16x16x32_bf16(qh[0], kh0, acc, 0, 0, 0);
            acc = __builtin_amdgcn_mfma_f32_16x16x32_bf16(ql[0], kh0, acc, 0, 0, 0);
            acc = __builtin_amdgcn_mfma_f32_16x16x32_bf16(qh[0], kl0, acc, 0, 0, 0);
            acc = __builtin_amdgcn_mfma_f32_16x16x32_bf16(qh[1], kh1, acc, 0, 0, 0);
            acc = __builtin_amdgcn_mfma_f32_16x16x32_bf16(ql[1], kh1, acc, 0, 0, 0);
            acc = __builtin_amdgcn_mfma_f32_16x16x32_bf16(qh[1], kl1, acc, 0, 0, 0);
            const int midx = b * TK_ + key;
            bool masked;
            if (mmode == 2)      masked = ((const u16*)maskp)[midx] != 0;
            else if (mmode == 3) masked = ((const float*)maskp)[midx] != 0.0f;
            else if (mmode == 1) masked = ((const unsigned char*)maskp)[midx] != 0;
            else                 masked = ((const int*)maskp)[midx] != 0;
            const int kk = wave * 128 + t * 16 + l16;
#pragma unroll
            for (int r = 0; r < 4; ++r)
                lg[quad * 4 + r][kk] = masked ? -3.0e38f : definite(acc[r], -3.0e38f);
        }
        __syncthreads();

        // ---- group-parallel top-64 merge (each 16-lane group owns one row)
        unsigned um[36];
        int ck4[4];
#pragma unroll
        for (int j = 0; j < 32; ++j) um[j] = mono(lg[rowg][l16 + 16 * j]);
#pragma unroll
        for (int t = 0; t < 4; ++t) {
            um[32 + t] = mono(cval[rowg][l16 + 16 * t]);
            ck4[t] = ckey[rowg][l16 + 16 * t];
        }

        // X := max T s.t. count(u >= T) >= 64  (64th-largest mono value)
        unsigned X = 0u;
        bool done = false;
        for (int bit = 31; bit >= 0; --bit) {
            const unsigned C = X | (1u << bit);
            int c = 0;
#pragma unroll
            for (int j = 0; j < 36; ++j) c += (um[j] >= C) ? 1 : 0;
            c = gsum16(c);
            if (!done && c >= 64) X = C;
            if (c == 64) done = true;
            if (__all(done)) break;
        }

        // compact strictly-greater
        int myGt = 0;
#pragma unroll
        for (int j = 0; j < 36; ++j) myGt += (um[j] > X) ? 1 : 0;
        const int totalGt = gsum16(myGt);
        int pre = myGt;
#pragma unroll
        for (int off = 1; off < 16; off <<= 1) {
            const int tv = __shfl_up(pre, off);
            if (l16 >= off) pre += tv;
        }
        int wpos = pre - myGt;
#pragma unroll
        for (int j = 0; j < 36; ++j) {
            if (um[j] > X) {
                cval[rowg][wpos] = invmono(um[j]);
                ckey[rowg][wpos] = (j < 32) ? (qtr * 512 + l16 + 16 * j) : ck4[j - 32];
                ++wpos;
            }
        }
        // tie-fill remaining slots with ==X entries, ascending key
        const float xval = invmono(X);
        int remaining = 64 - totalGt;
        int pos = totalGt;
        int lastkey = -1;
        while (remaining > 0) {
            int mykey = 0x7FFFFFFF;
#pragma unroll
            for (int j = 0; j < 36; ++j) {
                if (um[j] == X) {
                    const int kk = (j < 32) ? (qtr * 512 + l16 + 16 * j) : ck4[j - 32];
                    if (kk > lastkey && kk < mykey) mykey = kk;
                }
            }
            const int mn = gmin16(mykey);
            if (mn == 0x7FFFFFFF) break;
            if (mykey == mn) { cval[rowg][pos] = xval; ckey[rowg][pos] = mn; }
            lastkey = mn;
            ++pos; --remaining;
        }
        __syncthreads();   // lg rewritten next quarter by all waves
    }

    // ---- softmax over 64 kept entries (group-parallel, 4 vals/lane)
    {
        float v4[4];
#pragma unroll
        for (int t = 0; t < 4; ++t) v4[t] = cval[rowg][l16 + 16 * t];
        float m = fmaxf(fmaxf(v4[0], v4[1]), fmaxf(v4[2], v4[3]));
        m = gmax16f(m);
        float p4[4], S = 0.f;
#pragma unroll
        for (int t = 0; t < 4; ++t) { p4[t] = __expf(v4[t] - m); S += p4[t]; }
        S = gsum16f(S);
        const float inv = 1.0f / S;
#pragma unroll
        for (int t = 0; t < 4; ++t) cval[rowg][l16 + 16 * t] = p4[t] * inv;
    }
    // same-wave LDS write->read below (lockstep, compiler inserts lgkmcnt)

    // ---- weighted bf16-V gather: (w,k) via uniform LDS broadcast reads
    const u16* Vbase = Vb16 + (size_t)b * TK_ * DQ_ + h * DH_ + lane;
    for (int rr = 0; rr < 4; ++rr) {
        const int row = wave * 4 + rr;
        float av = 0.f;
#pragma unroll 4
        for (int e = 0; e < 64; ++e) {
            const float w = cval[row][e];
            const int k = ckey[row][e];
            av += w * bf2f(Vbase[(size_t)k * DQ_]);
        }
        av = definite(av, 0.0f);
        const size_t o = (size_t)(b * TQ_ + q0 + row) * DQ_ + h * DH_ + lane;
        const u16 hi = f2bf(av);
        attnH[o] = hi;
        attnL[o] = f2bf(av - bf2f(hi));
    }
}

// ---------------------------------------------------------------------------
extern "C" void kernel_launch(void* const* d_in, const int* in_sizes, int n_in,
                              void* d_out, int out_size, void* d_ws, size_t ws_size,
                              hipStream_t stream) {
    static const int exp_sizes[11] = {2097152, 3145728, 4096, 1048576, 1024,
                                      786432, 1024, 786432, 1024, 1048576, 1024};
    if (n_in != 11) {
        marker_kernel<<<(out_size + 255) / 256, 256, 0, stream>>>((float*)d_out, out_size,
                                                                  (float)(150 + n_in));
        return;
    }
    for (int i = 0; i < 11; ++i)
        if (in_sizes[i] != exp_sizes[i]) {
            marker_kernel<<<(out_size + 255) / 256, 256, 0, stream>>>((float*)d_out, out_size,
                                                                      (float)(200 + i));
            return;
        }

    const float* x   = (const float*)d_in[0];
    const float* ctx = (const float*)d_in[1];
    const void*  msk = d_in[2];
    const float* Wq = (const float*)d_in[3];
    const float* bq = (const float*)d_in[4];
    const float* Wk = (const float*)d_in[5];
    const float* bk = (const float*)d_in[6];
    const float* Wv = (const float*)d_in[7];
    const float* bv = (const float*)d_in[8];
    const float* Wo = (const float*)d_in[9];
    const float* bo = (const float*)d_in[10];

    // ---- workspace: exactly 32 MB (verified sufficient in round 4)
    const size_t SZ_Q = (size_t)BN_ * TQ_ * DQ_ * 2;   // 4 MB
    const size_t SZ_K = (size_t)BN_ * TK_ * DQ_ * 2;   // 8 MB
    const size_t NEED = 2 * SZ_Q + 2 * SZ_K + SZ_K;    // 32 MB
    if (ws_size < NEED) {
        marker_kernel<<<(out_size + 255) / 256, 256, 0, stream>>>(
            (float*)d_out, out_size, (float)(ws_size >> 20));
        return;
    }

    char* ws = (char*)d_ws;
    u16* Qhi = (u16*)(ws);
    u16* Qlo = (u16*)(ws + SZ_Q);
    u16* Khi = (u16*)(ws + 2 * SZ_Q);
    u16* Klo = (u16*)(ws + 2 * SZ_Q + SZ_K);
    u16* Vb  = (u16*)(ws + 2 * SZ_Q + 2 * SZ_K);

    // weight-split scratch carved from regions that are dead at that moment:
    u16* WqT_h = Khi;                      // Khi unwritten until K-proj
    u16* WqT_l = Khi + (size_t)DQ_ * DQ_;
    u16* WkT_h = Vb;                       // Vb unwritten until V-proj
    u16* WkT_l = Vb + (size_t)DC_ * DQ_;
    u16* WvT_h = (u16*)d_out;              // d_out dead until final GEMM
    u16* WvT_l = (u16*)d_out + (size_t)DC_ * DQ_;
    u16* WoT_h = Khi;                      // Khi dead after attention
    u16* WoT_l = Khi + (size_t)DQ_ * DQ_;

    const int MQ = BN_ * TQ_;  // 2048
    const int MK = BN_ * TK_;  // 4096

    // Q projection (scale DH^-0.5 folded into the hi/lo split)
    tsplit<<<dim3(DQ_ / 32, DQ_ / 32), 256, 0, stream>>>(Wq, WqT_h, WqT_l, DQ_, DQ_);
    gemm2<0, 2><<<dim3(DQ_ / 64, MQ / 64), 256, 0, stream>>>(
        x, nullptr, WqT_h, WqT_l, bq, 0.125f, Qhi, Qlo, MQ, DQ_, DQ_);
    // K projection
    tsplit<<<dim3(DQ_ / 32, DC_ / 32), 256, 0, stream>>>(Wk, WkT_h, WkT_l, DC_, DQ_);
    gemm2<0, 2><<<dim3(DQ_ / 64, MK / 64), 256, 0, stream>>>(
        ctx, nullptr, WkT_h, WkT_l, bk, 1.0f, Khi, Klo, MK, DQ_, DC_);
    // V projection (bf16 out)
    tsplit<<<dim3(DQ_ / 32, DC_ / 32), 256, 0, stream>>>(Wv, WvT_h, WvT_l, DC_, DQ_);
    gemm2<0, 1><<<dim3(DQ_ / 64, MK / 64), 256, 0, stream>>>(
        ctx, nullptr, WvT_h, WvT_l, bv, 1.0f, Vb, nullptr, MK, DQ_, DC_);

    // fused top-64 attention; writes attn hi/lo in place over Qhi/Qlo
    attn_topk<<<dim3(TQ_ / 16, NH_, BN_), 256, 0, stream>>>(
        Qhi, Qlo, Khi, Klo, Vb, msk, Qhi, Qlo);

    // output projection: split-A (attn hi/lo), fp32 out
    tsplit<<<dim3(DQ_ / 32, DQ_ / 32), 256, 0, stream>>>(Wo, WoT_h, WoT_l, DQ_, DQ_);
    gemm2<1, 0><<<dim3(DQ_ / 64, MQ / 64), 256, 0, stream>>>(
        Qhi, Qlo, WoT_h, WoT_l, bo, 1.0f, d_out, nullptr, MQ, DQ_, DQ_);
}